// Round 1
// baseline (106.648 us; speedup 1.0000x reference)
//
#include <hip/hip_runtime.h>

#define NM 8     // marginals
#define NN 128   // nodes
#define NI 127   // intervals

#define GRID 2048
#define PT 8     // float4 per thread, all loaded up-front

// Banded rows (half-width 16) of the exact inverse of the [1,4,1] interior
// tridiagonal system (unknowns c[1..126]). Elements decay as (2-sqrt(3))^|i-j|
// ~ 0.268^k, so truncation at +-16 is exact to ~1e-9 relative. Stored
// transposed + padded for coalesced loads: WT[k][i] = Ainv[i][i-16+k] in
// c-index space, i in [0,127]; rows i=0 and i=127 are all-zero => c=0 there.
struct WTab { float v[33 * 128]; };
constexpr WTab make_wt() {
    WTab t{};
    double cp[NI];
    cp[0] = 0.0;
    for (int i = 1; i <= 126; ++i) cp[i] = 1.0 / (4.0 - cp[i - 1]);
    for (int i0 = 1; i0 <= 126; ++i0) {          // solve A w = e_{i0} (symmetric)
        double dp[NN] = {};
        double prev = 0.0;
        for (int i = 1; i <= 126; ++i) {
            double rhs = (i == i0) ? 1.0 : 0.0;
            prev = (rhs - prev) * cp[i];
            dp[i] = prev;
        }
        double w[NN] = {};
        double cn = 0.0;
        for (int i = 126; i >= 1; --i) {
            cn = dp[i] - cp[i] * cn;
            w[i] = cn;
        }
        for (int k = 0; k < 33; ++k) {
            int j = i0 - 16 + k;
            if (j >= 1 && j <= 126) t.v[k * 128 + i0] = (float)w[j];
        }
    }
    return t;
}
__constant__ WTab WT = make_wt();

typedef float f4v __attribute__((ext_vector_type(4)));

__device__ __forceinline__ float eval1(float xv, const float4* __restrict__ tab) {
    // reference bucketization: clamp(ceil(((x+4)/8)*127)-1, 0, 126)
    // done in float domain: fi == (float)idx exactly (small integers), so
    // y = fma(fi,-h,t) is bit-identical to the int-index formulation.
    float t  = xv + 4.0f;
    float fi = ceilf(t * 15.875f) - 1.0f;
    fi = fminf(fmaxf(fi, 0.0f), 126.0f);
    int idx = (int)fi;
    float y = fmaf(fi, -(8.0f / 127.0f), t);     // y = (x+4) - idx*h
    float4 co = tab[idx];                        // one ds_read_b128: (a,b,c,d)
    return fmaf(y, fmaf(y, fmaf(y, co.w, co.z), co.y), co.x);
}

// Fused: x-loads issued first (stream under preamble); single-marginal
// preamble (f is block-uniform: 256-thread block spans one 16384-gid window),
// fully-parallel banded coefficient build, fused float4 table, then eval.
__global__ __launch_bounds__(256)
void spline_fused_kernel(const f4v* __restrict__ x,
                         const float* __restrict__ nodal,
                         float* __restrict__ partials, int n4) {
    __shared__ float  rhsPad[160];   // 640 B (16-pad both sides, zeroed)
    __shared__ float  sc[NN];        // 512 B
    __shared__ float4 tab[NI];       // 2032 B  (a,b,c,d) fused
    __shared__ float  wsum[4];

    const int tid = threadIdx.x;
    const int gid = blockIdx.x * 256 + tid;
    const int S   = GRID * 256;          // k*S/16384 = k*32 -> f invariant
    const int f   = (gid >> 14) & 7;     // block-uniform

    // --- 1) issue ALL x loads first; they stay in flight during the preamble ---
    f4v v[PT];
    bool full = (gid + (PT - 1) * S < n4);
    if (full) {
        #pragma unroll
        for (int k = 0; k < PT; ++k)
            v[k] = __builtin_nontemporal_load(&x[gid + k * S]);
    }

    // --- 2) padded rhs for THIS block's marginal only (640 B) ---
    const float inv_h2 = (127.0f / 8.0f) * (127.0f / 8.0f);
    if (tid < 160) {
        int jc = tid - 16;               // c-index
        float val = 0.0f;
        if (jc >= 1 && jc <= 126)
            val = 3.0f * (nodal[f * NN + jc - 1] - 2.0f * nodal[f * NN + jc]
                          + nodal[f * NN + jc + 1]) * inv_h2;
        rhsPad[tid] = val;
    }
    __syncthreads();

    // --- 3) c = Ainv * rhs via banded weights (fully parallel, 33 FMAs) ---
    if (tid < NN) {
        float a0 = 0.f;
        for (int k = 0; k < 33; ++k)
            a0 = fmaf(WT.v[k * 128 + tid], rhsPad[tid + k], a0);  // coalesced, L1-hot
        sc[tid] = a0;
    }
    __syncthreads();

    // --- 4) fused (a,b,c,d) table ---
    const float h = 8.0f / 127.0f, inv_h = 127.0f / 8.0f;
    if (tid < NI) {
        float ci  = sc[tid];
        float ci1 = sc[tid + 1];
        float a = nodal[f * NN + tid];
        float b = (nodal[f * NN + tid + 1] - a) * inv_h - h * (2.0f * ci + ci1) * (1.0f / 3.0f);
        float d = (ci1 - ci) * inv_h * (1.0f / 3.0f);
        tab[tid] = make_float4(a, b, ci, d);
    }
    __syncthreads();

    // --- 5) evaluate (x values already in registers); same accumulation order
    //        as the verified baseline -> bit-identical partial sums ---
    float acc = 0.0f;
    if (full) {
        #pragma unroll
        for (int k = 0; k < PT; ++k) {
            acc += eval1(v[k].x, tab);
            acc += eval1(v[k].y, tab);
            acc += eval1(v[k].z, tab);
            acc += eval1(v[k].w, tab);
        }
    } else {
        for (int k = 0; k < PT; ++k) {
            int i = gid + k * S;
            if (i < n4) {
                f4v vv = x[i];
                acc += eval1(vv.x, tab); acc += eval1(vv.y, tab);
                acc += eval1(vv.z, tab); acc += eval1(vv.w, tab);
            }
        }
    }

    // --- 6) wave-64 reduce -> LDS -> per-block partial (plain store) ---
    #pragma unroll
    for (int off = 32; off > 0; off >>= 1) acc += __shfl_down(acc, off);
    int lane = tid & 63;
    int wid  = tid >> 6;
    if (lane == 0) wsum[wid] = acc;
    __syncthreads();
    if (tid == 0) partials[blockIdx.x] = wsum[0] + wsum[1] + wsum[2] + wsum[3];
}

// 1 block: sum GRID partials, plain store (no pre-zero of out needed).
__global__ __launch_bounds__(256)
void final_reduce_kernel(const float* __restrict__ partials, float* __restrict__ out) {
    __shared__ float wsum[4];
    float a = 0.0f;
    for (int i = threadIdx.x; i < GRID; i += 256) a += partials[i];
    #pragma unroll
    for (int off = 32; off > 0; off >>= 1) a += __shfl_down(a, off);
    int lane = threadIdx.x & 63, wid = threadIdx.x >> 6;
    if (lane == 0) wsum[wid] = a;
    __syncthreads();
    if (threadIdx.x == 0) out[0] = wsum[0] + wsum[1] + wsum[2] + wsum[3];
}

extern "C" void kernel_launch(void* const* d_in, const int* in_sizes, int n_in,
                              void* d_out, int out_size, void* d_ws, size_t ws_size,
                              hipStream_t stream) {
    const float* x     = (const float*)d_in[0];
    const float* nodal = (const float*)d_in[1];
    float* out      = (float*)d_out;
    float* partials = (float*)d_ws;      // GRID floats

    int n4 = in_sizes[0] / 4;            // 4,194,304 = GRID*256*PT exactly

    spline_fused_kernel<<<GRID, 256, 0, stream>>>((const f4v*)x, nodal, partials, n4);
    final_reduce_kernel<<<1, 256, 0, stream>>>(partials, out);
}

// Round 2
// 103.643 us; speedup vs baseline: 1.0290x; 1.0290x over previous
//
#include <hip/hip_runtime.h>

#define NM 8     // marginals
#define NN 128   // nodes
#define NI 127   // intervals

#define GRID 2048
#define PT 8     // float4 per thread, all loaded up-front

// Banded rows (half-width 16) of the exact inverse of the [1,4,1] interior
// tridiagonal system (unknowns c[1..126]). Elements decay as (2-sqrt(3))^|i-j|
// ~ 0.268^k, so truncation at +-16 is exact to ~1e-9 relative. Stored
// transposed + padded for coalesced loads: WT[k][i] = Ainv[i][i-16+k] in
// c-index space, i in [0,127]; rows i=0 and i=127 are all-zero => c=0 there.
struct WTab { float v[33 * 128]; };
constexpr WTab make_wt() {
    WTab t{};
    double cp[NI];
    cp[0] = 0.0;
    for (int i = 1; i <= 126; ++i) cp[i] = 1.0 / (4.0 - cp[i - 1]);
    for (int i0 = 1; i0 <= 126; ++i0) {          // solve A w = e_{i0} (symmetric)
        double dp[NN] = {};
        double prev = 0.0;
        for (int i = 1; i <= 126; ++i) {
            double rhs = (i == i0) ? 1.0 : 0.0;
            prev = (rhs - prev) * cp[i];
            dp[i] = prev;
        }
        double w[NN] = {};
        double cn = 0.0;
        for (int i = 126; i >= 1; --i) {
            cn = dp[i] - cp[i] * cn;
            w[i] = cn;
        }
        for (int k = 0; k < 33; ++k) {
            int j = i0 - 16 + k;
            if (j >= 1 && j <= 126) t.v[k * 128 + i0] = (float)w[j];
        }
    }
    return t;
}
__constant__ WTab WT = make_wt();

typedef float f4v __attribute__((ext_vector_type(4)));

__device__ __forceinline__ float eval1(float xv,
                                       const float2* __restrict__ tAB,
                                       const float2* __restrict__ tCD) {
    // reference bucketization: clamp(ceil(((x+4)/8)*127)-1, 0, 126)
    // float-domain clamp: fi == (float)idx exactly (small integers), so
    // y = fma(fi,-h,t) is bit-identical to the int-index formulation.
    float t  = xv + 4.0f;
    float fi = ceilf(t * 15.875f) - 1.0f;
    fi = fminf(fmaxf(fi, 0.0f), 126.0f);
    int idx = (int)fi;
    float y = fmaf(fi, -(8.0f / 127.0f), t);     // y = (x+4) - idx*h
    // two b64 gathers (2 banks/lane, ~4-way avg -> 1.58x) instead of one
    // b128 (4 banks/lane, ~8-way avg -> 2.9x): LDS pipe stays under the
    // HBM-stream shadow.
    float2 ab = tAB[idx];
    float2 cd = tCD[idx];
    return fmaf(y, fmaf(y, fmaf(y, cd.y, cd.x), ab.y), ab.x);
}

// Fused: x-loads issued first (stream under preamble); single-marginal
// preamble (f is block-uniform: a 256-thread block spans one 16384-gid
// window), fully-parallel banded coefficient build, then eval.
__global__ __launch_bounds__(256)
void spline_fused_kernel(const f4v* __restrict__ x,
                         const float* __restrict__ nodal,
                         float* __restrict__ partials, int n4) {
    __shared__ float  rhsPad[160];     // 640 B (16-pad both sides, zeroed)
    __shared__ float  sc[NN];          // 512 B
    __shared__ float2 tabAB[NI];       // 1016 B
    __shared__ float2 tabCD[NI];       // 1016 B
    __shared__ float  wsum[4];

    const int tid = threadIdx.x;
    const int gid = blockIdx.x * 256 + tid;
    const int S   = GRID * 256;          // k*S/16384 = k*32 -> f invariant
    const int f   = (gid >> 14) & 7;     // block-uniform

    // --- 1) issue ALL x loads first; they stay in flight during the preamble ---
    f4v v[PT];
    bool full = (gid + (PT - 1) * S < n4);
    if (full) {
        #pragma unroll
        for (int k = 0; k < PT; ++k) v[k] = x[gid + k * S];
    }

    // --- 2) padded rhs for THIS block's marginal only (640 B) ---
    const float inv_h2 = (127.0f / 8.0f) * (127.0f / 8.0f);
    if (tid < 160) {
        int jc = tid - 16;               // c-index
        float val = 0.0f;
        if (jc >= 1 && jc <= 126)
            val = 3.0f * (nodal[f * NN + jc - 1] - 2.0f * nodal[f * NN + jc]
                          + nodal[f * NN + jc + 1]) * inv_h2;
        rhsPad[tid] = val;
    }
    __syncthreads();

    // --- 3) c = Ainv * rhs via banded weights (fully parallel, 33 FMAs) ---
    if (tid < NN) {
        float a0 = 0.f;
        for (int k = 0; k < 33; ++k)
            a0 = fmaf(WT.v[k * 128 + tid], rhsPad[tid + k], a0);  // coalesced, L1-hot
        sc[tid] = a0;
    }
    __syncthreads();

    // --- 4) (a,b)/(c,d) tables ---
    const float h = 8.0f / 127.0f, inv_h = 127.0f / 8.0f;
    if (tid < NI) {
        float ci  = sc[tid];
        float ci1 = sc[tid + 1];
        float a = nodal[f * NN + tid];
        float b = (nodal[f * NN + tid + 1] - a) * inv_h - h * (2.0f * ci + ci1) * (1.0f / 3.0f);
        float d = (ci1 - ci) * inv_h * (1.0f / 3.0f);
        tabAB[tid] = make_float2(a, b);
        tabCD[tid] = make_float2(ci, d);
    }
    __syncthreads();

    // --- 5) evaluate (x values already in registers); same accumulation order
    //        as the verified baseline -> bit-identical partial sums ---
    float acc = 0.0f;
    if (full) {
        #pragma unroll
        for (int k = 0; k < PT; ++k) {
            acc += eval1(v[k].x, tabAB, tabCD);
            acc += eval1(v[k].y, tabAB, tabCD);
            acc += eval1(v[k].z, tabAB, tabCD);
            acc += eval1(v[k].w, tabAB, tabCD);
        }
    } else {
        for (int k = 0; k < PT; ++k) {
            int i = gid + k * S;
            if (i < n4) {
                f4v vv = x[i];
                acc += eval1(vv.x, tabAB, tabCD); acc += eval1(vv.y, tabAB, tabCD);
                acc += eval1(vv.z, tabAB, tabCD); acc += eval1(vv.w, tabAB, tabCD);
            }
        }
    }

    // --- 6) wave-64 reduce -> LDS -> per-block partial (plain store) ---
    #pragma unroll
    for (int off = 32; off > 0; off >>= 1) acc += __shfl_down(acc, off);
    int lane = tid & 63;
    int wid  = tid >> 6;
    if (lane == 0) wsum[wid] = acc;
    __syncthreads();
    if (tid == 0) partials[blockIdx.x] = wsum[0] + wsum[1] + wsum[2] + wsum[3];
}

// 1 block: sum GRID partials, plain store (no pre-zero of out needed).
__global__ __launch_bounds__(256)
void final_reduce_kernel(const float* __restrict__ partials, float* __restrict__ out) {
    __shared__ float wsum[4];
    float a = 0.0f;
    for (int i = threadIdx.x; i < GRID; i += 256) a += partials[i];
    #pragma unroll
    for (int off = 32; off > 0; off >>= 1) a += __shfl_down(a, off);
    int lane = threadIdx.x & 63, wid = threadIdx.x >> 6;
    if (lane == 0) wsum[wid] = a;
    __syncthreads();
    if (threadIdx.x == 0) out[0] = wsum[0] + wsum[1] + wsum[2] + wsum[3];
}

extern "C" void kernel_launch(void* const* d_in, const int* in_sizes, int n_in,
                              void* d_out, int out_size, void* d_ws, size_t ws_size,
                              hipStream_t stream) {
    const float* x     = (const float*)d_in[0];
    const float* nodal = (const float*)d_in[1];
    float* out      = (float*)d_out;
    float* partials = (float*)d_ws;      // GRID floats

    int n4 = in_sizes[0] / 4;            // 4,194,304 = GRID*256*PT exactly

    spline_fused_kernel<<<GRID, 256, 0, stream>>>((const f4v*)x, nodal, partials, n4);
    final_reduce_kernel<<<1, 256, 0, stream>>>(partials, out);
}

// Round 3
// 96.787 us; speedup vs baseline: 1.1019x; 1.0708x over previous
//
#include <hip/hip_runtime.h>

#define NM 8     // marginals
#define NN 128   // nodes
#define NI 127   // intervals

#define GRID 2048
#define PT 8     // float4 per thread, consumed chunk-wise (SW pipeline depth 3)

// Banded rows (half-width 16) of the exact inverse of the [1,4,1] interior
// tridiagonal system (unknowns c[1..126]). Elements decay as (2-sqrt(3))^|i-j|
// ~ 0.268^k, so truncation at +-16 is exact to ~1e-9 relative. Stored
// transposed + padded for coalesced loads: WT[k][i] = Ainv[i][i-16+k] in
// c-index space, i in [0,127]; rows i=0 and i=127 are all-zero => c=0 there.
struct WTab { float v[33 * 128]; };
constexpr WTab make_wt() {
    WTab t{};
    double cp[NI];
    cp[0] = 0.0;
    for (int i = 1; i <= 126; ++i) cp[i] = 1.0 / (4.0 - cp[i - 1]);
    for (int i0 = 1; i0 <= 126; ++i0) {          // solve A w = e_{i0} (symmetric)
        double dp[NN] = {};
        double prev = 0.0;
        for (int i = 1; i <= 126; ++i) {
            double rhs = (i == i0) ? 1.0 : 0.0;
            prev = (rhs - prev) * cp[i];
            dp[i] = prev;
        }
        double w[NN] = {};
        double cn = 0.0;
        for (int i = 126; i >= 1; --i) {
            cn = dp[i] - cp[i] * cn;
            w[i] = cn;
        }
        for (int k = 0; k < 33; ++k) {
            int j = i0 - 16 + k;
            if (j >= 1 && j <= 126) t.v[k * 128 + i0] = (float)w[j];
        }
    }
    return t;
}
__constant__ WTab WT = make_wt();

typedef float f4v __attribute__((ext_vector_type(4)));

__device__ __forceinline__ float eval1(float xv,
                                       const float2* __restrict__ tAB,
                                       const float2* __restrict__ tCD) {
    // reference bucketization: clamp(ceil(((x+4)/8)*127)-1, 0, 126)
    // float-domain clamp: fi == (float)idx exactly (small integers), so
    // y = fma(fi,-h,t) is bit-identical to the int-index formulation.
    float t  = xv + 4.0f;
    float fi = ceilf(t * 15.875f) - 1.0f;
    fi = fminf(fmaxf(fi, 0.0f), 126.0f);
    int idx = (int)fi;
    float y = fmaf(fi, -(8.0f / 127.0f), t);     // y = (x+4) - idx*h
    // two b64 gathers (2 banks/lane) -- proven layout (R1's b128 regressed)
    float2 ab = tAB[idx];
    float2 cd = tCD[idx];
    return fmaf(y, fmaf(y, fmaf(y, cd.y, cd.x), ab.y), ab.x);
}

// KEY CHANGE vs R2: x loads are issued AFTER the last __syncthreads.
// The compiler emits s_waitcnt vmcnt(0) before every s_barrier, so loads
// issued before the preamble were fully drained at the first barrier --
// back-loading all eval work after the entire 64MB stream. Now each wave
// consumes chunk k while chunks k+1..k+3 are still in flight (progressive
// vmcnt waits), hiding eval under the stream.
__global__ __launch_bounds__(256)
void spline_fused_kernel(const f4v* __restrict__ x,
                         const float* __restrict__ nodal,
                         float* __restrict__ partials, int n4) {
    __shared__ float  rhsPad[160];     // 640 B (16-pad both sides, zeroed)
    __shared__ float  sc[NN];          // 512 B
    __shared__ float2 tabAB[NI];       // 1016 B
    __shared__ float2 tabCD[NI];       // 1016 B
    __shared__ float  wsum[4];

    const int tid = threadIdx.x;
    const int gid = blockIdx.x * 256 + tid;
    const int S   = GRID * 256;          // k*S/16384 = k*32 -> f invariant
    const int f   = (gid >> 14) & 7;     // block-uniform

    // --- 1) padded rhs for THIS block's marginal only (640 B) ---
    const float inv_h2 = (127.0f / 8.0f) * (127.0f / 8.0f);
    if (tid < 160) {
        int jc = tid - 16;               // c-index
        float val = 0.0f;
        if (jc >= 1 && jc <= 126)
            val = 3.0f * (nodal[f * NN + jc - 1] - 2.0f * nodal[f * NN + jc]
                          + nodal[f * NN + jc + 1]) * inv_h2;
        rhsPad[tid] = val;
    }
    __syncthreads();

    // --- 2) c = Ainv * rhs via banded weights (fully parallel, 33 FMAs) ---
    if (tid < NN) {
        float a0 = 0.f;
        for (int k = 0; k < 33; ++k)
            a0 = fmaf(WT.v[k * 128 + tid], rhsPad[tid + k], a0);  // coalesced, L1-hot
        sc[tid] = a0;
    }
    __syncthreads();

    // --- 3) (a,b)/(c,d) tables ---
    const float h = 8.0f / 127.0f, inv_h = 127.0f / 8.0f;
    if (tid < NI) {
        float ci  = sc[tid];
        float ci1 = sc[tid + 1];
        float a = nodal[f * NN + tid];
        float b = (nodal[f * NN + tid + 1] - a) * inv_h - h * (2.0f * ci + ci1) * (1.0f / 3.0f);
        float d = (ci1 - ci) * inv_h * (1.0f / 3.0f);
        tabAB[tid] = make_float2(a, b);
        tabCD[tid] = make_float2(ci, d);
    }
    __syncthreads();   // last barrier BEFORE any x load

    // --- 4) software-pipelined stream + eval (depth 3) ---
    const float2* __restrict__ tAB = tabAB;
    const float2* __restrict__ tCD = tabCD;

    float acc = 0.0f;
    bool full = (gid + (PT - 1) * S < n4);
    if (full) {
        f4v v[PT];                       // fully-unrolled static indexing only
        v[0] = x[gid];
        v[1] = x[gid + S];
        v[2] = x[gid + 2 * S];
        #pragma unroll
        for (int k = 0; k < PT; ++k) {
            if (k + 3 < PT) v[k + 3] = x[gid + (k + 3) * S];  // prefetch depth 3
            acc += eval1(v[k].x, tAB, tCD);
            acc += eval1(v[k].y, tAB, tCD);
            acc += eval1(v[k].z, tAB, tCD);
            acc += eval1(v[k].w, tAB, tCD);
        }
    } else {
        for (int k = 0; k < PT; ++k) {
            int i = gid + k * S;
            if (i < n4) {
                f4v vv = x[i];
                acc += eval1(vv.x, tAB, tCD); acc += eval1(vv.y, tAB, tCD);
                acc += eval1(vv.z, tAB, tCD); acc += eval1(vv.w, tAB, tCD);
            }
        }
    }

    // --- 5) wave-64 reduce -> LDS -> per-block partial (plain store) ---
    #pragma unroll
    for (int off = 32; off > 0; off >>= 1) acc += __shfl_down(acc, off);
    int lane = tid & 63;
    int wid  = tid >> 6;
    if (lane == 0) wsum[wid] = acc;
    __syncthreads();
    if (tid == 0) partials[blockIdx.x] = wsum[0] + wsum[1] + wsum[2] + wsum[3];
}

// 1 block: sum GRID partials, plain store (no pre-zero of out needed).
__global__ __launch_bounds__(256)
void final_reduce_kernel(const float* __restrict__ partials, float* __restrict__ out) {
    __shared__ float wsum[4];
    float a = 0.0f;
    for (int i = threadIdx.x; i < GRID; i += 256) a += partials[i];
    #pragma unroll
    for (int off = 32; off > 0; off >>= 1) a += __shfl_down(a, off);
    int lane = threadIdx.x & 63, wid = threadIdx.x >> 6;
    if (lane == 0) wsum[wid] = a;
    __syncthreads();
    if (threadIdx.x == 0) out[0] = wsum[0] + wsum[1] + wsum[2] + wsum[3];
}

extern "C" void kernel_launch(void* const* d_in, const int* in_sizes, int n_in,
                              void* d_out, int out_size, void* d_ws, size_t ws_size,
                              hipStream_t stream) {
    const float* x     = (const float*)d_in[0];
    const float* nodal = (const float*)d_in[1];
    float* out      = (float*)d_out;
    float* partials = (float*)d_ws;      // GRID floats

    int n4 = in_sizes[0] / 4;            // 4,194,304 = GRID*256*PT exactly

    spline_fused_kernel<<<GRID, 256, 0, stream>>>((const f4v*)x, nodal, partials, n4);
    final_reduce_kernel<<<1, 256, 0, stream>>>(partials, out);
}